// Round 25
// baseline (5176.153 us; speedup 1.0000x reference)
//

#include <hip/hip_runtime.h>
#include <hip/hip_bf16.h>

#define CIN   1024
#define FEATN 64
#define HH    48
#define WW    160
#define DDN   48
#define HWN   7680
#define PLANE 491520          // FEATN*HWN elements (one y1 d-plane)
#define EPSV  1e-5f

// ---------------------------------------------------------------------------
// down_sample: 1x1 conv (64 out x 1024 in over 7680 positions) + BN + ReLU
// grid (120, 2): x = 64-position tile, y = image (0=L, 1=R). 256 threads.
// Output: f32 [o][h*W+w] into workspace.
// ---------------------------------------------------------------------------
__global__ void CostVolume_6201932775918_ds(
    const float* Lf, const float* Rf,
    const float* dsw, const float* dsb,
    const float* g2, const float* b2, const float* m2, const float* v2,
    float* outL, float* outR)
{
    const float* in = (blockIdx.y == 0) ? Lf : Rf;
    float* out = (blockIdx.y == 0) ? outL : outR;
    const int t    = (int)threadIdx.x;
    const int pos0 = (int)blockIdx.x * 64;
    const int oq   = t & 15;
    const int pq   = t >> 4;

    __shared__ float chunk[64 * 64];

    float acc[4][4];
    #pragma unroll
    for (int k = 0; k < 4; ++k)
        #pragma unroll
        for (int j = 0; j < 4; ++j) acc[k][j] = 0.f;

    for (int cc = 0; cc < 16; ++cc) {
        __syncthreads();
        #pragma unroll
        for (int i = 0; i < 16; ++i) {
            int idx = i * 256 + t;
            int cl = idx >> 6;
            int p  = idx & 63;
            chunk[cl * 64 + p] = in[(cc * 64 + cl) * HWN + pos0 + p];
        }
        __syncthreads();
        for (int cl = 0; cl < 64; ++cl) {
            int c = cc * 64 + cl;
            float x0 = chunk[cl * 64 + pq * 4 + 0];
            float x1 = chunk[cl * 64 + pq * 4 + 1];
            float x2 = chunk[cl * 64 + pq * 4 + 2];
            float x3 = chunk[cl * 64 + pq * 4 + 3];
            #pragma unroll
            for (int k = 0; k < 4; ++k) {
                float w = dsw[(oq + 16 * k) * CIN + c];
                acc[k][0] = fmaf(w, x0, acc[k][0]);
                acc[k][1] = fmaf(w, x1, acc[k][1]);
                acc[k][2] = fmaf(w, x2, acc[k][2]);
                acc[k][3] = fmaf(w, x3, acc[k][3]);
            }
        }
    }

    #pragma unroll
    for (int k = 0; k < 4; ++k) {
        int o = oq + 16 * k;
        float s  = g2[o] / sqrtf(v2[o] + EPSV);
        float cb = dsb[o] * s + b2[o] - m2[o] * s;
        #pragma unroll
        for (int j = 0; j < 4; ++j) {
            float r = fmaxf(0.f, fmaf(acc[k][j], s, cb));
            out[o * HWN + pos0 + pq * 4 + j] = r;
        }
    }
}

// ---------------------------------------------------------------------------
// conv3a over the implicit cost volume (128 in-ch, 3x3x3) + BN + ReLU -> y1
// cost[ci,d,h,w] = ci<64 ? (w>=d ? L[ci,h,w] : 0) : (w>=d ? R[ci-64,h,w-d] : 0)
// grid (5, 48, 48): x = 32-wide w tile, y = h, z = d. y1 layout [d][o][h][w] f32.
// ---------------------------------------------------------------------------
__global__ void CostVolume_6201932775918_c3a(
    const float* L, const float* R,
    const float* w3, const float* cb3,
    const float* g3, const float* b3, const float* m3, const float* v3,
    float* y1)
{
    const int d  = (int)blockIdx.z;
    const int t  = (int)threadIdx.x;
    const int w0 = (int)blockIdx.x * 32;
    const int h  = (int)blockIdx.y;
    const int o    = t >> 2;
    const int wsub = t & 3;

    __shared__ float slab[128 * 36];

    float acc[8];
    #pragma unroll
    for (int j = 0; j < 8; ++j) acc[j] = 0.f;

    for (int kd = 0; kd < 3; ++kd) {
        const int dp = d + kd - 1;
        if (dp < 0 || dp >= DDN) continue;
        for (int kh = 0; kh < 3; ++kh) {
            const int hp = h + kh - 1;
            if (hp < 0 || hp >= HH) continue;
            __syncthreads();
            for (int i = 0; i < 17; ++i) {
                int idx = i * 256 + t;
                int ci = idx / 34;
                int wi = idx % 34;
                int wp = w0 + wi - 1;
                float val = 0.f;
                if (wp >= dp && wp < WW) {
                    if (ci < 64)
                        val = L[ci * HWN + hp * WW + wp];
                    else
                        val = R[(ci - 64) * HWN + hp * WW + (wp - dp)];
                }
                slab[ci * 36 + wi] = val;
            }
            __syncthreads();
            const float* wb = w3 + o * 3456 + kd * 9 + kh * 3;
            for (int ci = 0; ci < 128; ++ci) {
                float wa = wb[ci * 27 + 0];
                float wc = wb[ci * 27 + 1];
                float we = wb[ci * 27 + 2];
                const float* sp = slab + ci * 36 + wsub * 8;
                float vv[10];
                #pragma unroll
                for (int q = 0; q < 10; ++q) vv[q] = sp[q];
                #pragma unroll
                for (int j = 0; j < 8; ++j)
                    acc[j] = fmaf(vv[j], wa, fmaf(vv[j + 1], wc, fmaf(vv[j + 2], we, acc[j])));
            }
        }
    }

    float s  = g3[o] / sqrtf(v3[o] + EPSV);
    float cbv = cb3[o] * s + b3[o] - m3[o] * s;
    int obase = d * PLANE + o * HWN + h * WW + w0 + wsub * 8;
    #pragma unroll
    for (int j = 0; j < 8; ++j) {
        float r = fmaxf(0.f, fmaf(acc[j], s, cbv));
        y1[obase + j] = r;
    }
}

// ---------------------------------------------------------------------------
// conv3b (64 in-ch, 3x3x3, input y1 f32) + BN + ReLU -> d_out (FLOAT32!)
// Output layout: ((o*D + d)*H + h)*W + w (reference reshape(B,-1,H,W)).
// ---------------------------------------------------------------------------
__global__ void CostVolume_6201932775918_c3b(
    const float* y1,
    const float* w3, const float* cb3,
    const float* g3, const float* b3, const float* m3, const float* v3,
    float* outp)
{
    const int d  = (int)blockIdx.z;
    const int t  = (int)threadIdx.x;
    const int w0 = (int)blockIdx.x * 32;
    const int h  = (int)blockIdx.y;
    const int o    = t >> 2;
    const int wsub = t & 3;

    __shared__ float slab[64 * 36];

    float acc[8];
    #pragma unroll
    for (int j = 0; j < 8; ++j) acc[j] = 0.f;

    for (int kd = 0; kd < 3; ++kd) {
        const int dp = d + kd - 1;
        if (dp < 0 || dp >= DDN) continue;
        const float* yplane = y1 + (size_t)dp * PLANE;
        for (int kh = 0; kh < 3; ++kh) {
            const int hp = h + kh - 1;
            if (hp < 0 || hp >= HH) continue;
            __syncthreads();
            for (int i = 0; i < 9; ++i) {
                int idx = i * 256 + t;
                if (idx < 2176) {
                    int ci = idx / 34;
                    int wi = idx % 34;
                    int wp = w0 + wi - 1;
                    float val = 0.f;
                    if (wp >= 0 && wp < WW)
                        val = yplane[ci * HWN + hp * WW + wp];
                    slab[ci * 36 + wi] = val;
                }
            }
            __syncthreads();
            const float* wb = w3 + o * 1728 + kd * 9 + kh * 3;
            for (int ci = 0; ci < 64; ++ci) {
                float wa = wb[ci * 27 + 0];
                float wc = wb[ci * 27 + 1];
                float we = wb[ci * 27 + 2];
                const float* sp = slab + ci * 36 + wsub * 8;
                float vv[10];
                #pragma unroll
                for (int q = 0; q < 10; ++q) vv[q] = sp[q];
                #pragma unroll
                for (int j = 0; j < 8; ++j)
                    acc[j] = fmaf(vv[j], wa, fmaf(vv[j + 1], wc, fmaf(vv[j + 2], we, acc[j])));
            }
        }
    }

    float s  = g3[o] / sqrtf(v3[o] + EPSV);
    float cbv = cb3[o] * s + b3[o] - m3[o] * s;
    int obase = ((o * DDN + d) * HH + h) * WW + w0 + wsub * 8;
    #pragma unroll
    for (int j = 0; j < 8; ++j) {
        float r = fmaxf(0.f, fmaf(acc[j], s, cbv));
        outp[obase + j] = r;
    }
}

// ---------------------------------------------------------------------------
extern "C" void kernel_launch(void* const* d_in, const int* in_sizes, int n_in,
                              void* d_out, int out_size, void* d_ws, size_t ws_size,
                              hipStream_t stream)
{
    (void)in_sizes; (void)n_in; (void)out_size;

    const float* Lf  = (const float*)d_in[0];
    const float* Rf  = (const float*)d_in[1];
    const float* dsw = (const float*)d_in[2];
    const float* dsb = (const float*)d_in[3];
    const float* g2  = (const float*)d_in[4];
    const float* b2  = (const float*)d_in[5];
    const float* m2  = (const float*)d_in[6];
    const float* v2  = (const float*)d_in[7];
    const float* w3a = (const float*)d_in[8];
    const float* cba = (const float*)d_in[9];
    const float* g3a = (const float*)d_in[10];
    const float* b3a = (const float*)d_in[11];
    const float* m3a = (const float*)d_in[12];
    const float* v3a = (const float*)d_in[13];
    const float* w3b = (const float*)d_in[14];
    const float* cbb = (const float*)d_in[15];
    const float* g3b = (const float*)d_in[16];
    const float* b3b = (const float*)d_in[17];
    const float* m3b = (const float*)d_in[18];
    const float* v3b = (const float*)d_in[19];

    float* outF = (float*)d_out;       // OUTPUT IS FLOAT32 (reference is f32)

    // Workspace (f32): [ L PLANE ][ R PLANE ][ y1 48*PLANE ] = 98.3 MB
    float* Lds = (float*)d_ws;
    float* Rds = Lds + PLANE;
    float* y1  = Rds + PLANE;
    // ws_size is >= 4*out_nbytes = 377 MB per harness formula — always fits.
    if (ws_size < (size_t)(2 + 48) * PLANE * 4) return;

    CostVolume_6201932775918_ds<<<dim3(120, 2), 256, 0, stream>>>(
        Lf, Rf, dsw, dsb, g2, b2, m2, v2, Lds, Rds);

    CostVolume_6201932775918_c3a<<<dim3(5, 48, 48), 256, 0, stream>>>(
        Lds, Rds, w3a, cba, g3a, b3a, m3a, v3a, y1);

    CostVolume_6201932775918_c3b<<<dim3(5, 48, 48), 256, 0, stream>>>(
        y1, w3b, cbb, g3b, b3b, m3b, v3b, outF);
}

// Round 26
// 2588.329 us; speedup vs baseline: 1.9998x; 1.9998x over previous
//

#include <hip/hip_runtime.h>
#include <hip/hip_bf16.h>

#define CIN   1024
#define FEATN 64
#define HH    48
#define WW    160
#define DDN   48
#define HWN   7680
#define PLANE 491520          // FEATN*HWN (one y1 d-plane, elements)
#define EPSV  1e-5f
#define NTAP  27
#define WSLAB 162             // w index range [-1..160] -> wIdx 0..161

typedef __attribute__((ext_vector_type(8))) short bf16x8;
typedef __attribute__((ext_vector_type(4))) float f32x4;

static __device__ __forceinline__ unsigned short f2bf(float x) {
    __hip_bfloat16 h = __float2bfloat16(x);
    return *(unsigned short*)&h;
}

// ---------------------------------------------------------------------------
// Pack conv3a weights: Wb[o][tap][ci] (bf16) from w3a[o][ci][kd][kh][kw] (f32)
// tap = (kd*3+kh)*3+kw. 64*27*128 = 221184 elements.
// ---------------------------------------------------------------------------
__global__ void CostVolume_6201932775918_packw(const float* w3, unsigned short* Wb)
{
    int i = (int)(blockIdx.x * 256 + threadIdx.x);
    if (i >= 64 * NTAP * 128) return;
    int ci  = i & 127;
    int tap = (i >> 7) % NTAP;
    int o   = i / (NTAP * 128);
    Wb[i] = f2bf(w3[o * 3456 + ci * 27 + tap]);
}

// ---------------------------------------------------------------------------
// down_sample: 1x1 conv + BN + ReLU -> bf16 L/R [o][h*W+w]
// ---------------------------------------------------------------------------
__global__ void CostVolume_6201932775918_ds(
    const float* Lf, const float* Rf,
    const float* dsw, const float* dsb,
    const float* g2, const float* b2, const float* m2, const float* v2,
    unsigned short* outL, unsigned short* outR)
{
    const float* in = (blockIdx.y == 0) ? Lf : Rf;
    unsigned short* out = (blockIdx.y == 0) ? outL : outR;
    const int t    = (int)threadIdx.x;
    const int pos0 = (int)blockIdx.x * 64;
    const int oq   = t & 15;
    const int pq   = t >> 4;

    __shared__ float chunk[64 * 64];

    float acc[4][4];
    #pragma unroll
    for (int k = 0; k < 4; ++k)
        #pragma unroll
        for (int j = 0; j < 4; ++j) acc[k][j] = 0.f;

    for (int cc = 0; cc < 16; ++cc) {
        __syncthreads();
        #pragma unroll
        for (int i = 0; i < 16; ++i) {
            int idx = i * 256 + t;
            int cl = idx >> 6;
            int p  = idx & 63;
            chunk[cl * 64 + p] = in[(cc * 64 + cl) * HWN + pos0 + p];
        }
        __syncthreads();
        for (int cl = 0; cl < 64; ++cl) {
            int c = cc * 64 + cl;
            float x0 = chunk[cl * 64 + pq * 4 + 0];
            float x1 = chunk[cl * 64 + pq * 4 + 1];
            float x2 = chunk[cl * 64 + pq * 4 + 2];
            float x3 = chunk[cl * 64 + pq * 4 + 3];
            #pragma unroll
            for (int k = 0; k < 4; ++k) {
                float w = dsw[(oq + 16 * k) * CIN + c];
                acc[k][0] = fmaf(w, x0, acc[k][0]);
                acc[k][1] = fmaf(w, x1, acc[k][1]);
                acc[k][2] = fmaf(w, x2, acc[k][2]);
                acc[k][3] = fmaf(w, x3, acc[k][3]);
            }
        }
    }

    #pragma unroll
    for (int k = 0; k < 4; ++k) {
        int o = oq + 16 * k;
        float s  = g2[o] / sqrtf(v2[o] + EPSV);
        float cb = dsb[o] * s + b2[o] - m2[o] * s;
        #pragma unroll
        for (int j = 0; j < 4; ++j) {
            float r = fmaxf(0.f, fmaf(acc[k][j], s, cb));
            out[o * HWN + pos0 + pq * 4 + j] = f2bf(r);
        }
    }
}

// ---------------------------------------------------------------------------
// conv3a via bf16 MFMA implicit GEMM + BN + ReLU -> y1 (f32, [d][o][h][w])
// Block = (h, d), 4 waves. M=64 (o), N=160 (w). Wave m: o-rows [16m,16m+16).
// Per (kd,kh): stage cost slab transposed [wIdx][ci] bf16 (XOR-swizzled),
// then for kw, ci-chunk: A = packed weights (global), B = slab, 10 MFMAs.
// cost[ci,d,h,w] = ci<64 ? (w>=d ? L[ci,h,w] : 0) : (w>=d ? R[ci-64,h,w-d] : 0)
// ---------------------------------------------------------------------------
__global__ __launch_bounds__(256) void CostVolume_6201932775918_c3a(
    const unsigned short* Lb, const unsigned short* Rb,
    const unsigned short* Wb,
    const float* cb3, const float* g3, const float* b3,
    const float* m3, const float* v3,
    float* y1)
{
    const int h    = (int)blockIdx.x;   // 0..47
    const int d    = (int)blockIdx.y;   // 0..47
    const int t    = (int)threadIdx.x;
    const int wave = t >> 6;            // 0..3  (M quarter)
    const int lane = t & 63;
    const int l15  = lane & 15;
    const int lhi  = lane >> 4;         // 0..3

    __shared__ unsigned short slab[WSLAB * 128];   // 41472 B; byte=(wIdx*256+ci*2)^((wIdx&15)<<4)

    f32x4 acc[10];
    #pragma unroll
    for (int n = 0; n < 10; ++n) acc[n] = (f32x4){0.f, 0.f, 0.f, 0.f};

    char* slabB = (char*)slab;

    for (int kd = 0; kd < 3; ++kd) {
        const int dp = d + kd - 1;
        if (dp < 0 || dp >= DDN) continue;
        for (int kh = 0; kh < 3; ++kh) {
            const int hp = h + kh - 1;
            if (hp < 0 || hp >= HH) continue;
            __syncthreads();
            // ---- stage transposed slab: e = ci*WSLAB + wIdx ----
            for (int i = 0; i < 81; ++i) {
                int e = i * 256 + t;                 // 0..20735 (81*256=20736=128*162)
                int ci = e / WSLAB;
                int wIdx = e - ci * WSLAB;
                int wp = wIdx - 1;
                unsigned short val = 0;
                if (wp >= dp && wp < WW) {           // dp>=0 => wp>=0; mask w'>=d'
                    val = (ci < 64) ? Lb[ci * HWN + hp * WW + wp]
                                    : Rb[(ci - 64) * HWN + hp * WW + (wp - dp)];
                }
                int byte = (wIdx * 256 + ci * 2) ^ ((wIdx & 15) << 4);
                *(unsigned short*)(slabB + byte) = val;
            }
            __syncthreads();
            // ---- MFMA: 3 kw x 4 ci-chunks x 10 n-tiles ----
            const int tapbase = (kd * 3 + kh) * 3;
            #pragma unroll
            for (int kw = 0; kw < 3; ++kw) {
                const unsigned short* wrow =
                    Wb + (16 * wave + l15) * (NTAP * 128) + (tapbase + kw) * 128 + lhi * 8;
                #pragma unroll
                for (int kc = 0; kc < 4; ++kc) {
                    bf16x8 afrag = *(const bf16x8*)(wrow + kc * 32);
                    const int ci0x2 = (kc * 32 + lhi * 8) * 2;
                    #pragma unroll
                    for (int n = 0; n < 10; ++n) {
                        int wIdx = 16 * n + l15 + kw;      // col w' = wIdx-1
                        int byte = (wIdx * 256 + ci0x2) ^ ((wIdx & 15) << 4);
                        bf16x8 bfrag = *(const bf16x8*)(slabB + byte);
                        acc[n] = __builtin_amdgcn_mfma_f32_16x16x32_bf16(
                            afrag, bfrag, acc[n], 0, 0, 0);
                    }
                }
            }
        }
    }

    // ---- epilogue: BN + ReLU -> y1 f32. D: col(w)=l15, row(o_loc)=lhi*4+r ----
    #pragma unroll
    for (int r = 0; r < 4; ++r) {
        const int o = 16 * wave + lhi * 4 + r;
        const float s  = g3[o] / sqrtf(v3[o] + EPSV);
        const float cbv = cb3[o] * s + b3[o] - m3[o] * s;
        float* yrow = y1 + (size_t)d * PLANE + o * HWN + h * WW;
        #pragma unroll
        for (int n = 0; n < 10; ++n) {
            int w = 16 * n + l15;
            yrow[w] = fmaxf(0.f, fmaf(acc[n][r], s, cbv));
        }
    }
}

// ---------------------------------------------------------------------------
// conv3b (64 in-ch, 3x3x3, y1 f32) + BN + ReLU -> d_out (f32)  [unchanged]
// ---------------------------------------------------------------------------
__global__ void CostVolume_6201932775918_c3b(
    const float* y1,
    const float* w3, const float* cb3,
    const float* g3, const float* b3, const float* m3, const float* v3,
    float* outp)
{
    const int d  = (int)blockIdx.z;
    const int t  = (int)threadIdx.x;
    const int w0 = (int)blockIdx.x * 32;
    const int h  = (int)blockIdx.y;
    const int o    = t >> 2;
    const int wsub = t & 3;

    __shared__ float slab[64 * 36];

    float acc[8];
    #pragma unroll
    for (int j = 0; j < 8; ++j) acc[j] = 0.f;

    for (int kd = 0; kd < 3; ++kd) {
        const int dp = d + kd - 1;
        if (dp < 0 || dp >= DDN) continue;
        const float* yplane = y1 + (size_t)dp * PLANE;
        for (int kh = 0; kh < 3; ++kh) {
            const int hp = h + kh - 1;
            if (hp < 0 || hp >= HH) continue;
            __syncthreads();
            for (int i = 0; i < 9; ++i) {
                int idx = i * 256 + t;
                if (idx < 2176) {
                    int ci = idx / 34;
                    int wi = idx % 34;
                    int wp = w0 + wi - 1;
                    float val = 0.f;
                    if (wp >= 0 && wp < WW)
                        val = yplane[ci * HWN + hp * WW + wp];
                    slab[ci * 36 + wi] = val;
                }
            }
            __syncthreads();
            const float* wb = w3 + o * 1728 + kd * 9 + kh * 3;
            for (int ci = 0; ci < 64; ++ci) {
                float wa = wb[ci * 27 + 0];
                float wc = wb[ci * 27 + 1];
                float we = wb[ci * 27 + 2];
                const float* sp = slab + ci * 36 + wsub * 8;
                float vv[10];
                #pragma unroll
                for (int q = 0; q < 10; ++q) vv[q] = sp[q];
                #pragma unroll
                for (int j = 0; j < 8; ++j)
                    acc[j] = fmaf(vv[j], wa, fmaf(vv[j + 1], wc, fmaf(vv[j + 2], we, acc[j])));
            }
        }
    }

    float s  = g3[o] / sqrtf(v3[o] + EPSV);
    float cbv = cb3[o] * s + b3[o] - m3[o] * s;
    int obase = ((o * DDN + d) * HH + h) * WW + w0 + wsub * 8;
    #pragma unroll
    for (int j = 0; j < 8; ++j) {
        float r = fmaxf(0.f, fmaf(acc[j], s, cbv));
        outp[obase + j] = r;
    }
}

// ---------------------------------------------------------------------------
extern "C" void kernel_launch(void* const* d_in, const int* in_sizes, int n_in,
                              void* d_out, int out_size, void* d_ws, size_t ws_size,
                              hipStream_t stream)
{
    (void)in_sizes; (void)n_in; (void)out_size;

    const float* Lf  = (const float*)d_in[0];
    const float* Rf  = (const float*)d_in[1];
    const float* dsw = (const float*)d_in[2];
    const float* dsb = (const float*)d_in[3];
    const float* g2  = (const float*)d_in[4];
    const float* b2  = (const float*)d_in[5];
    const float* m2  = (const float*)d_in[6];
    const float* v2  = (const float*)d_in[7];
    const float* w3a = (const float*)d_in[8];
    const float* cba = (const float*)d_in[9];
    const float* g3a = (const float*)d_in[10];
    const float* b3a = (const float*)d_in[11];
    const float* m3a = (const float*)d_in[12];
    const float* v3a = (const float*)d_in[13];
    const float* w3b = (const float*)d_in[14];
    const float* cbb = (const float*)d_in[15];
    const float* g3b = (const float*)d_in[16];
    const float* b3b = (const float*)d_in[17];
    const float* m3b = (const float*)d_in[18];
    const float* v3b = (const float*)d_in[19];

    float* outF = (float*)d_out;       // output dtype: FLOAT32

    // ws layout (bytes):
    //   Lb  bf16 @ 0         (983,040)
    //   Rb  bf16 @ 983,040   (983,040)
    //   Wb  bf16 @ 1,966,080 (442,368)
    //   y1  f32  @ 2,408,448 (94,371,840)   total ~96.8 MB (ws = 377 MB)
    unsigned short* Lb = (unsigned short*)d_ws;
    unsigned short* Rb = (unsigned short*)((char*)d_ws + 983040);
    unsigned short* Wb = (unsigned short*)((char*)d_ws + 1966080);
    float*          y1 = (float*)((char*)d_ws + 2408448);
    if (ws_size < 2408448 + (size_t)PLANE * DDN / 64 * 64 * 4) return;

    CostVolume_6201932775918_packw<<<dim3(864), 256, 0, stream>>>(w3a, Wb);

    CostVolume_6201932775918_ds<<<dim3(120, 2), 256, 0, stream>>>(
        Lf, Rf, dsw, dsb, g2, b2, m2, v2, Lb, Rb);

    CostVolume_6201932775918_c3a<<<dim3(48, 48), 256, 0, stream>>>(
        Lb, Rb, Wb, cba, g3a, b3a, m3a, v3a, y1);

    CostVolume_6201932775918_c3b<<<dim3(5, 48, 48), 256, 0, stream>>>(
        y1, w3b, cbb, g3b, b3b, m3b, v3b, outF);
}

// Round 27
// 1282.269 us; speedup vs baseline: 4.0367x; 2.0186x over previous
//

#include <hip/hip_runtime.h>
#include <hip/hip_bf16.h>

#define CIN   1024
#define FEATN 64
#define HH    48
#define WW    160
#define DDN   48
#define HWN   7680
#define PLANE 491520          // FEATN*HWN (one y1 d-plane, elements)
#define EPSV  1e-5f
#define NTAP  27
#define WSLAB 162             // w index range [-1..160] -> wIdx 0..161

typedef __attribute__((ext_vector_type(8))) short bf16x8;
typedef __attribute__((ext_vector_type(4))) float f32x4;

static __device__ __forceinline__ unsigned short f2bf(float x) {
    __hip_bfloat16 h = __float2bfloat16(x);
    return *(unsigned short*)&h;
}

// ---------------------------------------------------------------------------
// Pack conv3a weights: Wb[o][tap][ci128] bf16 from w3a[o][ci][tap] f32
// ---------------------------------------------------------------------------
__global__ void CostVolume_6201932775918_packw(const float* w3, unsigned short* Wb)
{
    int i = (int)(blockIdx.x * 256 + threadIdx.x);
    if (i >= 64 * NTAP * 128) return;
    int ci  = i & 127;
    int tap = (i >> 7) % NTAP;
    int o   = i / (NTAP * 128);
    Wb[i] = f2bf(w3[o * 3456 + ci * 27 + tap]);
}

// ---------------------------------------------------------------------------
// Pack conv3b weights: Wb2[o][tap][ci64] bf16 from w3b[o][ci][tap] f32
// ---------------------------------------------------------------------------
__global__ void CostVolume_6201932775918_packw2(const float* w3, unsigned short* Wb2)
{
    int i = (int)(blockIdx.x * 256 + threadIdx.x);
    if (i >= 64 * NTAP * 64) return;
    int ci  = i & 63;
    int tap = (i >> 6) % NTAP;
    int o   = i / (NTAP * 64);
    Wb2[i] = f2bf(w3[o * 1728 + ci * 27 + tap]);
}

// ---------------------------------------------------------------------------
// down_sample: 1x1 conv + BN + ReLU -> bf16 L/R [o][h*W+w]
// ---------------------------------------------------------------------------
__global__ void CostVolume_6201932775918_ds(
    const float* Lf, const float* Rf,
    const float* dsw, const float* dsb,
    const float* g2, const float* b2, const float* m2, const float* v2,
    unsigned short* outL, unsigned short* outR)
{
    const float* in = (blockIdx.y == 0) ? Lf : Rf;
    unsigned short* out = (blockIdx.y == 0) ? outL : outR;
    const int t    = (int)threadIdx.x;
    const int pos0 = (int)blockIdx.x * 64;
    const int oq   = t & 15;
    const int pq   = t >> 4;

    __shared__ float chunk[64 * 64];

    float acc[4][4];
    #pragma unroll
    for (int k = 0; k < 4; ++k)
        #pragma unroll
        for (int j = 0; j < 4; ++j) acc[k][j] = 0.f;

    for (int cc = 0; cc < 16; ++cc) {
        __syncthreads();
        #pragma unroll
        for (int i = 0; i < 16; ++i) {
            int idx = i * 256 + t;
            int cl = idx >> 6;
            int p  = idx & 63;
            chunk[cl * 64 + p] = in[(cc * 64 + cl) * HWN + pos0 + p];
        }
        __syncthreads();
        for (int cl = 0; cl < 64; ++cl) {
            int c = cc * 64 + cl;
            float x0 = chunk[cl * 64 + pq * 4 + 0];
            float x1 = chunk[cl * 64 + pq * 4 + 1];
            float x2 = chunk[cl * 64 + pq * 4 + 2];
            float x3 = chunk[cl * 64 + pq * 4 + 3];
            #pragma unroll
            for (int k = 0; k < 4; ++k) {
                float w = dsw[(oq + 16 * k) * CIN + c];
                acc[k][0] = fmaf(w, x0, acc[k][0]);
                acc[k][1] = fmaf(w, x1, acc[k][1]);
                acc[k][2] = fmaf(w, x2, acc[k][2]);
                acc[k][3] = fmaf(w, x3, acc[k][3]);
            }
        }
    }

    #pragma unroll
    for (int k = 0; k < 4; ++k) {
        int o = oq + 16 * k;
        float s  = g2[o] / sqrtf(v2[o] + EPSV);
        float cb = dsb[o] * s + b2[o] - m2[o] * s;
        #pragma unroll
        for (int j = 0; j < 4; ++j) {
            float r = fmaxf(0.f, fmaf(acc[k][j], s, cb));
            out[o * HWN + pos0 + pq * 4 + j] = f2bf(r);
        }
    }
}

// ---------------------------------------------------------------------------
// conv3a via bf16 MFMA implicit GEMM + BN + ReLU -> y1 (BF16, [d][o][h][w])
// Block = (h, d), 4 waves. M=64 (o), N=160 (w). Wave m: o-rows [16m,16m+16).
// ---------------------------------------------------------------------------
__global__ __launch_bounds__(256) void CostVolume_6201932775918_c3a(
    const unsigned short* Lb, const unsigned short* Rb,
    const unsigned short* Wb,
    const float* cb3, const float* g3, const float* b3,
    const float* m3, const float* v3,
    unsigned short* y1)
{
    const int h    = (int)blockIdx.x;
    const int d    = (int)blockIdx.y;
    const int t    = (int)threadIdx.x;
    const int wave = t >> 6;
    const int lane = t & 63;
    const int l15  = lane & 15;
    const int lhi  = lane >> 4;

    __shared__ unsigned short slab[WSLAB * 128];   // 41472 B

    f32x4 acc[10];
    #pragma unroll
    for (int n = 0; n < 10; ++n) acc[n] = (f32x4){0.f, 0.f, 0.f, 0.f};

    char* slabB = (char*)slab;

    for (int kd = 0; kd < 3; ++kd) {
        const int dp = d + kd - 1;
        if (dp < 0 || dp >= DDN) continue;
        for (int kh = 0; kh < 3; ++kh) {
            const int hp = h + kh - 1;
            if (hp < 0 || hp >= HH) continue;
            __syncthreads();
            for (int i = 0; i < 81; ++i) {
                int e = i * 256 + t;                 // 81*256 = 20736 = 128*162
                int ci = e / WSLAB;
                int wIdx = e - ci * WSLAB;
                int wp = wIdx - 1;
                unsigned short val = 0;
                if (wp >= dp && wp < WW) {
                    val = (ci < 64) ? Lb[ci * HWN + hp * WW + wp]
                                    : Rb[(ci - 64) * HWN + hp * WW + (wp - dp)];
                }
                int byte = (wIdx * 256 + ci * 2) ^ ((wIdx & 15) << 4);
                *(unsigned short*)(slabB + byte) = val;
            }
            __syncthreads();
            const int tapbase = (kd * 3 + kh) * 3;
            #pragma unroll
            for (int kw = 0; kw < 3; ++kw) {
                const unsigned short* wrow =
                    Wb + (16 * wave + l15) * (NTAP * 128) + (tapbase + kw) * 128 + lhi * 8;
                #pragma unroll
                for (int kc = 0; kc < 4; ++kc) {
                    bf16x8 afrag = *(const bf16x8*)(wrow + kc * 32);
                    const int ci0x2 = (kc * 32 + lhi * 8) * 2;
                    #pragma unroll
                    for (int n = 0; n < 10; ++n) {
                        int wIdx = 16 * n + l15 + kw;
                        int byte = (wIdx * 256 + ci0x2) ^ ((wIdx & 15) << 4);
                        bf16x8 bfrag = *(const bf16x8*)(slabB + byte);
                        acc[n] = __builtin_amdgcn_mfma_f32_16x16x32_bf16(
                            afrag, bfrag, acc[n], 0, 0, 0);
                    }
                }
            }
        }
    }

    #pragma unroll
    for (int r = 0; r < 4; ++r) {
        const int o = 16 * wave + lhi * 4 + r;
        const float s  = g3[o] / sqrtf(v3[o] + EPSV);
        const float cbv = cb3[o] * s + b3[o] - m3[o] * s;
        unsigned short* yrow = y1 + (size_t)d * PLANE + o * HWN + h * WW;
        #pragma unroll
        for (int n = 0; n < 10; ++n) {
            int w = 16 * n + l15;
            yrow[w] = f2bf(fmaxf(0.f, fmaf(acc[n][r], s, cbv)));
        }
    }
}

// ---------------------------------------------------------------------------
// conv3b via bf16 MFMA implicit GEMM + BN + ReLU -> d_out (f32)
// Same structure as c3a; K = 64 ci x 27 taps. y1 bf16 [d][o][h][w].
// Output layout: ((o*D + d)*H + h)*W + w.
// ---------------------------------------------------------------------------
__global__ __launch_bounds__(256) void CostVolume_6201932775918_c3b(
    const unsigned short* y1, const unsigned short* Wb2,
    const float* cb3, const float* g3, const float* b3,
    const float* m3, const float* v3,
    float* outp)
{
    const int h    = (int)blockIdx.x;
    const int d    = (int)blockIdx.y;
    const int t    = (int)threadIdx.x;
    const int wave = t >> 6;
    const int lane = t & 63;
    const int l15  = lane & 15;
    const int lhi  = lane >> 4;

    __shared__ unsigned short slab[WSLAB * 64];    // 20736 B

    f32x4 acc[10];
    #pragma unroll
    for (int n = 0; n < 10; ++n) acc[n] = (f32x4){0.f, 0.f, 0.f, 0.f};

    char* slabB = (char*)slab;

    for (int kd = 0; kd < 3; ++kd) {
        const int dp = d + kd - 1;
        if (dp < 0 || dp >= DDN) continue;
        const unsigned short* yplane = y1 + (size_t)dp * PLANE;
        for (int kh = 0; kh < 3; ++kh) {
            const int hp = h + kh - 1;
            if (hp < 0 || hp >= HH) continue;
            __syncthreads();
            for (int i = 0; i < 41; ++i) {
                int e = i * 256 + t;                 // need 64*162 = 10368
                if (e < WSLAB * 64) {
                    int ci = e / WSLAB;
                    int wIdx = e - ci * WSLAB;
                    int wp = wIdx - 1;
                    unsigned short val = 0;
                    if (wp >= 0 && wp < WW)
                        val = yplane[ci * HWN + hp * WW + wp];
                    int byte = (wIdx * 128 + ci * 2) ^ ((wIdx & 7) << 4);
                    *(unsigned short*)(slabB + byte) = val;
                }
            }
            __syncthreads();
            const int tapbase = (kd * 3 + kh) * 3;
            #pragma unroll
            for (int kw = 0; kw < 3; ++kw) {
                const unsigned short* wrow =
                    Wb2 + (16 * wave + l15) * (NTAP * 64) + (tapbase + kw) * 64 + lhi * 8;
                #pragma unroll
                for (int kc = 0; kc < 2; ++kc) {
                    bf16x8 afrag = *(const bf16x8*)(wrow + kc * 32);
                    const int ci0x2 = (kc * 32 + lhi * 8) * 2;
                    #pragma unroll
                    for (int n = 0; n < 10; ++n) {
                        int wIdx = 16 * n + l15 + kw;
                        int byte = (wIdx * 128 + ci0x2) ^ ((wIdx & 7) << 4);
                        bf16x8 bfrag = *(const bf16x8*)(slabB + byte);
                        acc[n] = __builtin_amdgcn_mfma_f32_16x16x32_bf16(
                            afrag, bfrag, acc[n], 0, 0, 0);
                    }
                }
            }
        }
    }

    #pragma unroll
    for (int r = 0; r < 4; ++r) {
        const int o = 16 * wave + lhi * 4 + r;
        const float s  = g3[o] / sqrtf(v3[o] + EPSV);
        const float cbv = cb3[o] * s + b3[o] - m3[o] * s;
        float* orow = outp + ((size_t)(o * DDN + d) * HH + h) * WW;
        #pragma unroll
        for (int n = 0; n < 10; ++n) {
            int w = 16 * n + l15;
            orow[w] = fmaxf(0.f, fmaf(acc[n][r], s, cbv));
        }
    }
}

// ---------------------------------------------------------------------------
extern "C" void kernel_launch(void* const* d_in, const int* in_sizes, int n_in,
                              void* d_out, int out_size, void* d_ws, size_t ws_size,
                              hipStream_t stream)
{
    (void)in_sizes; (void)n_in; (void)out_size;

    const float* Lf  = (const float*)d_in[0];
    const float* Rf  = (const float*)d_in[1];
    const float* dsw = (const float*)d_in[2];
    const float* dsb = (const float*)d_in[3];
    const float* g2  = (const float*)d_in[4];
    const float* b2  = (const float*)d_in[5];
    const float* m2  = (const float*)d_in[6];
    const float* v2  = (const float*)d_in[7];
    const float* w3a = (const float*)d_in[8];
    const float* cba = (const float*)d_in[9];
    const float* g3a = (const float*)d_in[10];
    const float* b3a = (const float*)d_in[11];
    const float* m3a = (const float*)d_in[12];
    const float* v3a = (const float*)d_in[13];
    const float* w3b = (const float*)d_in[14];
    const float* cbb = (const float*)d_in[15];
    const float* g3b = (const float*)d_in[16];
    const float* b3b = (const float*)d_in[17];
    const float* m3b = (const float*)d_in[18];
    const float* v3b = (const float*)d_in[19];

    float* outF = (float*)d_out;       // output dtype: FLOAT32

    // ws layout (bytes):
    //   Lb  bf16 @ 0         (  983,040)
    //   Rb  bf16 @   983,040 (  983,040)
    //   Wb  bf16 @ 1,966,080 (  442,368)
    //   Wb2 bf16 @ 2,408,448 (  221,184)
    //   y1  bf16 @ 2,629,632 (47,185,920)   total ~49.8 MB (ws = 377 MB)
    unsigned short* Lb  = (unsigned short*)d_ws;
    unsigned short* Rb  = (unsigned short*)((char*)d_ws + 983040);
    unsigned short* Wb  = (unsigned short*)((char*)d_ws + 1966080);
    unsigned short* Wb2 = (unsigned short*)((char*)d_ws + 2408448);
    unsigned short* y1  = (unsigned short*)((char*)d_ws + 2629632);
    if (ws_size < 2629632 + (size_t)PLANE * DDN * 2) return;

    CostVolume_6201932775918_packw<<<dim3(864), 256, 0, stream>>>(w3a, Wb);
    CostVolume_6201932775918_packw2<<<dim3(432), 256, 0, stream>>>(w3b, Wb2);

    CostVolume_6201932775918_ds<<<dim3(120, 2), 256, 0, stream>>>(
        Lf, Rf, dsw, dsb, g2, b2, m2, v2, Lb, Rb);

    CostVolume_6201932775918_c3a<<<dim3(48, 48), 256, 0, stream>>>(
        Lb, Rb, Wb, cba, g3a, b3a, m3a, v3a, y1);

    CostVolume_6201932775918_c3b<<<dim3(48, 48), 256, 0, stream>>>(
        y1, Wb2, cbb, g3b, b3b, m3b, v3b, outF);
}